// Round 8
// baseline (92.618 us; speedup 1.0000x reference)
//
#include <hip/hip_runtime.h>
#include <math.h>

#define K_ 32
#define D_ 8
#define CSTRIDE 48   // 36 tri + 8 zm + 1 cst + 3 pad per component (192 B)
#define S_ 4         // samples per thread

// ---------------------------------------------------------------------------
// Fused kernel, software-pipelined k-loop.
// Round-7 evidence: a rolled k-loop that blocks on each iteration's constant
// load runs convoy-style (load phase + compute phase serialize across the
// whole CU): ~2100 cyc/CU/k ~ 33 us, for BOTH smem and LDS constant paths.
// Fix: unroll-2 + double register buffer; ds_reads for k+1 are in flight
// while k computes -> max(LDS 1152, VALU 944) cyc/CU/k ~ 15.4 us.
//
// Phase 1 (lanes 0..31, redundant per block): constants into LDS.
// chol(tril(L)tril(L)^T + eps I) = tril(L)*sign; maha/logdet sign-invariant,
// eps O(1e-6) rel -> invert tril(L) directly. Log2 domain (v_exp_f32 = exp2):
//   Ci'  = L^{-1} * sqrt(log2e/2),  zm' = (L^{-1} mean) * sqrt(log2e/2)
//   cst2 = [log_softmax(pi)_k - 0.5*(2 sum log|L_ii| + D log 2pi)] * log2e
//   W_k(x) = cst2_k - sum_i ((Ci' x)_i - zm'_i)^2 ;  out = ln2 * LSE2_k W_k
// ---------------------------------------------------------------------------
__global__ __launch_bounds__(256) void gmm_fused(
    const float* __restrict__ x,
    const float* __restrict__ pi,
    const float* __restrict__ means,
    const float* __restrict__ chol,
    float* __restrict__ out, int N)
{
    __shared__ float cv[K_ * CSTRIDE];

    const int tid = threadIdx.x;
    if (tid < K_) {
        const int k = tid;

        float L[D_][D_];
#pragma unroll
        for (int i = 0; i < D_; ++i)
#pragma unroll
            for (int j = 0; j <= i; ++j)
                L[i][j] = chol[k * D_ * D_ + i * D_ + j];

        float rd[D_];
#pragma unroll
        for (int i = 0; i < D_; ++i) rd[i] = 1.f / L[i][i];

        float Ci[D_][D_];
#pragma unroll
        for (int j = 0; j < D_; ++j) {
            Ci[j][j] = rd[j];
#pragma unroll
            for (int i = j + 1; i < D_; ++i) {
                float s = 0.f;
#pragma unroll
                for (int m = j; m < i; ++m) s += L[i][m] * Ci[m][j];
                Ci[i][j] = -s * rd[i];
            }
        }

        float logdet = 0.f;
#pragma unroll
        for (int i = 0; i < D_; ++i) logdet += __logf(fabsf(L[i][i]));
        logdet *= 2.f;

        float zm[D_];
#pragma unroll
        for (int i = 0; i < D_; ++i) {
            float s = 0.f;
#pragma unroll
            for (int j = 0; j <= i; ++j) s += Ci[i][j] * means[k * D_ + j];
            zm[i] = s;
        }

        float mx = pi[0];
#pragma unroll
        for (int t = 1; t < K_; ++t) mx = fmaxf(mx, pi[t]);
        float se = 0.f;
#pragma unroll
        for (int t = 0; t < K_; ++t) se += __expf(pi[t] - mx);
        float lse = mx + __logf(se);

        const float LOG2PI = 1.8378770664093453f;
        const float LOG2E  = 1.4426950408889634f;
        const float SQH2   = 0.84932180028801905f;  // sqrt(0.5 * log2e)
        float cst2 = ((pi[k] - lse) - 0.5f * (logdet + (float)D_ * LOG2PI)) * LOG2E;

        float* p = cv + k * CSTRIDE;
        int t = 0;
#pragma unroll
        for (int i = 0; i < D_; ++i)
#pragma unroll
            for (int j = 0; j <= i; ++j) p[t++] = Ci[i][j] * SQH2;
#pragma unroll
        for (int i = 0; i < D_; ++i) p[36 + i] = zm[i] * SQH2;
        p[44] = cst2;
        p[45] = 0.f; p[46] = 0.f; p[47] = 0.f;
    }
    __syncthreads();

    const int q = N >> 2;  // N / S_
    const int t = blockIdx.x * 256 + tid;
    if (t >= q) return;

    float xv[S_][D_];
#pragma unroll
    for (int s = 0; s < S_; ++s) {
        const float4* xp = (const float4*)x + (size_t)(t + s * q) * 2;
        float4 a = xp[0], b = xp[1];
        xv[s][0] = a.x; xv[s][1] = a.y; xv[s][2] = a.z; xv[s][3] = a.w;
        xv[s][4] = b.x; xv[s][5] = b.y; xv[s][6] = b.z; xv[s][7] = b.w;
    }

    float m[S_], sm[S_];
#pragma unroll
    for (int s = 0; s < S_; ++s) { m[s] = -INFINITY; sm[s] = 0.f; }

    // body: accumulate one component's contribution from register buffer cf
    auto body = [&](const float* cf) {
        float w[S_];
#pragma unroll
        for (int s = 0; s < S_; ++s) w[s] = cf[44];
        int tt = 0;
#pragma unroll
        for (int i = 0; i < D_; ++i) {
            float z[S_];
#pragma unroll
            for (int s = 0; s < S_; ++s) z[s] = -cf[36 + i];
#pragma unroll
            for (int j = 0; j <= i; ++j)
#pragma unroll
                for (int s = 0; s < S_; ++s)
                    z[s] = fmaf(cf[tt + j], xv[s][j], z[s]);
            tt += i + 1;
#pragma unroll
            for (int s = 0; s < S_; ++s) w[s] = fmaf(-z[s], z[s], w[s]);
        }
#pragma unroll
        for (int s = 0; s < S_; ++s) {
            float d = w[s] - m[s];
            float e = exp2f(-fabsf(d));
            sm[s] = (d > 0.f) ? fmaf(sm[s], e, 1.f) : (sm[s] + e);
            m[s] = fmaxf(m[s], w[s]);
        }
    };

    const float4* base = (const float4*)cv;  // 12 float4 per component
    float4 cur[12], nxt[12];
#pragma unroll
    for (int qq = 0; qq < 12; ++qq) cur[qq] = base[qq];  // k = 0

#pragma unroll 1
    for (int k = 0; k < K_; k += 2) {
        const float4* pn = base + (k + 1) * 12;          // prefetch k+1
#pragma unroll
        for (int qq = 0; qq < 12; ++qq) nxt[qq] = pn[qq];
        body((const float*)cur);                          // compute k

        const float4* pc = base + (((k + 2) & (K_ - 1)) * 12);  // prefetch k+2 (wraps)
#pragma unroll
        for (int qq = 0; qq < 12; ++qq) cur[qq] = pc[qq];
        body((const float*)nxt);                          // compute k+1
    }

    const float LN2 = 0.69314718055994531f;
#pragma unroll
    for (int s = 0; s < S_; ++s)
        out[t + s * q] = (m[s] + log2f(sm[s])) * LN2;
}

extern "C" void kernel_launch(void* const* d_in, const int* in_sizes, int n_in,
                              void* d_out, int out_size, void* d_ws, size_t ws_size,
                              hipStream_t stream) {
    const float* x     = (const float*)d_in[0];
    const float* pi    = (const float*)d_in[1];
    const float* means = (const float*)d_in[2];
    const float* chol  = (const float*)d_in[3];
    float* out = (float*)d_out;

    int N = in_sizes[0] / D_;
    int q = N >> 2;  // threads = N / S_

    gmm_fused<<<(q + 255) / 256, 256, 0, stream>>>(x, pi, means, chol, out, N);
}

// Round 9
// 77.693 us; speedup vs baseline: 1.1921x; 1.1921x over previous
//
#include <hip/hip_runtime.h>
#include <math.h>

#define K_ 32
#define D_ 8
#define NF 48          // 36 quad + 8 lin + 1 const + 3 pad features
#define NTHREADS 256
#define NBLOCKS 1024

typedef _Float16 half8 __attribute__((ext_vector_type(8)));
typedef float f32x16 __attribute__((ext_vector_type(16)));

// ---------------------------------------------------------------------------
// MFMA reformulation. maha = (x-mu)^T A (x-mu), A = L^-T L^-1, expands to
// x^T A x - 2 b^T x + mu^T b (b = A mu). In log2 domain (alpha = 0.5*log2e):
//   W2[n][k] = sum_f V[k][f] * Y[n][f]
//   Y = [x_i*x_j (j<=i), x_i, 1, 0,0,0]
//   V = [-alpha*A_ii / -2alpha*A_ij, 2alpha*b_i, cst2 - alpha*mu^T b, 0..]
//   out = ln2 * log2(sum_k exp2(W2))   -- no max-subtract: W2 in (-80,-3),
//   far above f32 underflow (-126); dropped terms are < 2^-120 relative.
// GEMM: 3x v_mfma_f32_32x32x16_f16 per 32-sample tile, A-op = weights
// (M=components), B-op = features (N=samples). C-layout (m74/m101): row =
// (reg&3)+8*(reg>>2)+4*(lane>>5) = k, col = lane&31 = sample -> the
// k-reduction is 15 in-lane adds + one shfl_xor(32); store coalesced from
// half 0. No per-k loads of any kind in the sample loop.
// ---------------------------------------------------------------------------
__global__ __launch_bounds__(NTHREADS) void gmm_mfma(
    const float* __restrict__ x,
    const float* __restrict__ pi,
    const float* __restrict__ means,
    const float* __restrict__ chol,
    float* __restrict__ out, int N)
{
    // A-operand fragments (weights), f16, in MFMA A-layout:
    // lane l holds A[m=l&31][kk=8*(l>>5)+j] of step s  ->  ldsA[s][l][j]
    __shared__ __align__(16) _Float16 ldsA[3][64][8];

    const int tid = threadIdx.x;

    if (tid < K_) {
        const int k = tid;
        float L[D_][D_];
#pragma unroll
        for (int i = 0; i < D_; ++i)
#pragma unroll
            for (int j = 0; j <= i; ++j)
                L[i][j] = chol[k * 64 + i * 8 + j];

        float rd[D_];
#pragma unroll
        for (int i = 0; i < D_; ++i) rd[i] = 1.f / L[i][i];

        // Ci = L^{-1} (lower); chol(L L^T + eps I) = L*sign, sign-invariant
        float Ci[D_][D_];
#pragma unroll
        for (int j = 0; j < D_; ++j) {
            Ci[j][j] = rd[j];
#pragma unroll
            for (int i = j + 1; i < D_; ++i) {
                float s = 0.f;
#pragma unroll
                for (int m = j; m < i; ++m) s += L[i][m] * Ci[m][j];
                Ci[i][j] = -s * rd[i];
            }
        }

        float logdet = 0.f;
#pragma unroll
        for (int i = 0; i < D_; ++i) logdet += __logf(fabsf(L[i][i]));
        logdet *= 2.f;

        // A2 = Ci^T Ci (symmetric)
        float A2[D_][D_];
#pragma unroll
        for (int i = 0; i < D_; ++i)
#pragma unroll
            for (int j = 0; j <= i; ++j) {
                float s = 0.f;
#pragma unroll
                for (int m = i; m < D_; ++m) s += Ci[m][i] * Ci[m][j];
                A2[i][j] = s;
                A2[j][i] = s;
            }

        float mu[D_];
#pragma unroll
        for (int j = 0; j < D_; ++j) mu[j] = means[k * 8 + j];
        float b[D_], q = 0.f;
#pragma unroll
        for (int i = 0; i < D_; ++i) {
            float s = 0.f;
#pragma unroll
            for (int j = 0; j < D_; ++j) s += A2[i][j] * mu[j];
            b[i] = s;
            q += s * mu[i];
        }

        float mx = pi[0];
#pragma unroll
        for (int t = 1; t < K_; ++t) mx = fmaxf(mx, pi[t]);
        float se = 0.f;
#pragma unroll
        for (int t = 0; t < K_; ++t) se += __expf(pi[t] - mx);
        float lse = mx + __logf(se);

        const float LOG2PI = 1.8378770664093453f;
        const float LOG2E  = 1.4426950408889634f;
        const float ALPHA  = 0.72134752044448170f;  // 0.5 * log2e
        float cst2 = ((pi[k] - lse) - 0.5f * (logdet + 8.f * LOG2PI)) * LOG2E;

        float V[NF];
        int t = 0;
#pragma unroll
        for (int i = 0; i < D_; ++i)
#pragma unroll
            for (int j = 0; j <= i; ++j)
                V[t++] = (i == j) ? -ALPHA * A2[i][i] : -2.f * ALPHA * A2[i][j];
#pragma unroll
        for (int i = 0; i < D_; ++i) V[36 + i] = 2.f * ALPHA * b[i];
        V[44] = cst2 - ALPHA * q;
        V[45] = 0.f; V[46] = 0.f; V[47] = 0.f;

#pragma unroll
        for (int s = 0; s < 3; ++s)
#pragma unroll
            for (int h = 0; h < 2; ++h)
#pragma unroll
                for (int j = 0; j < 8; ++j)
                    ldsA[s][h * 32 + k][j] = (_Float16)V[16 * s + 8 * h + j];
    }
    __syncthreads();

    const int lane = tid & 63;
    const int m    = lane & 31;   // = component for A-frag, = sample for B-frag
    const bool h1  = lane >= 32;

    half8 wf[3];
#pragma unroll
    for (int s = 0; s < 3; ++s) wf[s] = *(const half8*)&ldsA[s][lane][0];

    const int ntiles = N >> 5;
    const int gw = blockIdx.x * (NTHREADS / 64) + (tid >> 6);
    const int nw = gridDim.x * (NTHREADS / 64);
    const float4* xp = (const float4*)x;
    const float LN2 = 0.69314718055994531f;

    for (int tile = gw; tile < ntiles; tile += nw) {
        const int n = tile * 32 + m;
        float4 a = xp[2 * n], b2 = xp[2 * n + 1];
        float xv[D_] = {a.x, a.y, a.z, a.w, b2.x, b2.y, b2.z, b2.w};

        float Y[NF];
        {
            int t = 0;
#pragma unroll
            for (int i = 0; i < D_; ++i)
#pragma unroll
                for (int j = 0; j <= i; ++j) Y[t++] = xv[i] * xv[j];
#pragma unroll
            for (int i = 0; i < D_; ++i) Y[36 + i] = xv[i];
            Y[44] = 1.f; Y[45] = 0.f; Y[46] = 0.f; Y[47] = 0.f;
        }

        f32x16 acc;
#pragma unroll
        for (int r = 0; r < 16; ++r) acc[r] = 0.f;

#pragma unroll
        for (int s = 0; s < 3; ++s) {
            half8 bf;
#pragma unroll
            for (int j = 0; j < 8; ++j) {
                float v = h1 ? Y[16 * s + 8 + j] : Y[16 * s + j];
                bf[j] = (_Float16)v;
            }
            acc = __builtin_amdgcn_mfma_f32_32x32x16_f16(wf[s], bf, acc, 0, 0, 0);
        }

        float tot = 0.f;
#pragma unroll
        for (int r = 0; r < 16; ++r) tot += exp2f(acc[r]);
        tot += __shfl_xor(tot, 32, 64);   // add the other half's 16 components
        float res = log2f(tot) * LN2;
        if (!h1) out[n] = res;            // lanes 0..31: coalesced 128B store
    }
}

extern "C" void kernel_launch(void* const* d_in, const int* in_sizes, int n_in,
                              void* d_out, int out_size, void* d_ws, size_t ws_size,
                              hipStream_t stream) {
    const float* x     = (const float*)d_in[0];
    const float* pi    = (const float*)d_in[1];
    const float* means = (const float*)d_in[2];
    const float* chol  = (const float*)d_in[3];
    float* out = (float*)d_out;

    int N = in_sizes[0] / D_;

    gmm_mfma<<<NBLOCKS, NTHREADS, 0, stream>>>(x, pi, means, chol, out, N);
}

// Round 10
// 74.342 us; speedup vs baseline: 1.2458x; 1.0451x over previous
//
#include <hip/hip_runtime.h>
#include <math.h>

#define K_ 32
#define D_ 8
#define NF 48          // 36 quad + 8 lin + 1 const + 3 pad features
#define NTHREADS 256
#define NBLOCKS 1024
#define TPW 4          // tiles per wave, fully unrolled, loads hoisted

typedef _Float16 half8 __attribute__((ext_vector_type(8)));
typedef float f32x16 __attribute__((ext_vector_type(16)));

// ---------------------------------------------------------------------------
// MFMA reformulation (round-9, first real win). maha = x^T A x - 2 b^T x +
// mu^T b with A = L^-T L^-1, b = A mu. In log2 domain (alpha = 0.5*log2e):
//   W2[n][k] = sum_f V[k][f] * Y[n][f],  Y = [x_i x_j (j<=i), x_i, 1, pad]
//   out = ln2 * log2(sum_k exp2(W2))  -- W2 in (-80,-3), no max-subtract
// 3x v_mfma_f32_32x32x16_f16 per 32-sample tile; A-op = weights (M=K_),
// B-op = features (N=samples). C-layout: row=k=(reg&3)+8*(reg>>2)+4*(lane>>5),
// col=sample=lane&31 -> k-reduce = 16 exp2 + 15 adds in-lane + 1 shfl_xor(32).
//
// Round-10 change: 4 tiles per wave, fully unrolled, ALL 8 x-loads issued
// before any compute (partial-vmcnt waits per tile). Round-9's per-tile
// load->wait->compute loop exposed ~900 cyc HBM latency per 270 cyc compute
// (the rounds-4..8 convoy disease, moved to VMEM); hoisting makes each wave
// expose only its first load, covered by 3 co-resident waves/SIMD.
// Grid covers tiles exactly: 1024 blk x 4 waves x 4 tiles = 16384 = N/32.
// ---------------------------------------------------------------------------
__global__ __launch_bounds__(NTHREADS) void gmm_mfma(
    const float* __restrict__ x,
    const float* __restrict__ pi,
    const float* __restrict__ means,
    const float* __restrict__ chol,
    float* __restrict__ out, int N)
{
    // A-operand fragments (weights), f16: lane l holds A[m=l&31][kk=8*(l>>5)+j]
    __shared__ __align__(16) _Float16 ldsA[3][64][8];

    const int tid = threadIdx.x;

    if (tid < K_) {
        const int k = tid;
        float L[D_][D_];
#pragma unroll
        for (int i = 0; i < D_; ++i)
#pragma unroll
            for (int j = 0; j <= i; ++j)
                L[i][j] = chol[k * 64 + i * 8 + j];

        float rd[D_];
#pragma unroll
        for (int i = 0; i < D_; ++i) rd[i] = 1.f / L[i][i];

        // Ci = L^{-1}; chol(LL^T + eps I) = L*sign, maha/logdet sign-invariant
        float Ci[D_][D_];
#pragma unroll
        for (int j = 0; j < D_; ++j) {
            Ci[j][j] = rd[j];
#pragma unroll
            for (int i = j + 1; i < D_; ++i) {
                float s = 0.f;
#pragma unroll
                for (int m = j; m < i; ++m) s += L[i][m] * Ci[m][j];
                Ci[i][j] = -s * rd[i];
            }
        }

        float logdet = 0.f;
#pragma unroll
        for (int i = 0; i < D_; ++i) logdet += __logf(fabsf(L[i][i]));
        logdet *= 2.f;

        // A2 = Ci^T Ci
        float A2[D_][D_];
#pragma unroll
        for (int i = 0; i < D_; ++i)
#pragma unroll
            for (int j = 0; j <= i; ++j) {
                float s = 0.f;
#pragma unroll
                for (int m = i; m < D_; ++m) s += Ci[m][i] * Ci[m][j];
                A2[i][j] = s;
                A2[j][i] = s;
            }

        float mu[D_];
#pragma unroll
        for (int j = 0; j < D_; ++j) mu[j] = means[k * 8 + j];
        float b[D_], q = 0.f;
#pragma unroll
        for (int i = 0; i < D_; ++i) {
            float s = 0.f;
#pragma unroll
            for (int j = 0; j < D_; ++j) s += A2[i][j] * mu[j];
            b[i] = s;
            q += s * mu[i];
        }

        float mx = pi[0];
#pragma unroll
        for (int t = 1; t < K_; ++t) mx = fmaxf(mx, pi[t]);
        float se = 0.f;
#pragma unroll
        for (int t = 0; t < K_; ++t) se += __expf(pi[t] - mx);
        float lse = mx + __logf(se);

        const float LOG2PI = 1.8378770664093453f;
        const float LOG2E  = 1.4426950408889634f;
        const float ALPHA  = 0.72134752044448170f;  // 0.5 * log2e
        float cst2 = ((pi[k] - lse) - 0.5f * (logdet + 8.f * LOG2PI)) * LOG2E;

        float V[NF];
        int t = 0;
#pragma unroll
        for (int i = 0; i < D_; ++i)
#pragma unroll
            for (int j = 0; j <= i; ++j)
                V[t++] = (i == j) ? -ALPHA * A2[i][i] : -2.f * ALPHA * A2[i][j];
#pragma unroll
        for (int i = 0; i < D_; ++i) V[36 + i] = 2.f * ALPHA * b[i];
        V[44] = cst2 - ALPHA * q;
        V[45] = 0.f; V[46] = 0.f; V[47] = 0.f;

#pragma unroll
        for (int s = 0; s < 3; ++s)
#pragma unroll
            for (int h = 0; h < 2; ++h)
#pragma unroll
                for (int j = 0; j < 8; ++j)
                    ldsA[s][h * 32 + k][j] = (_Float16)V[16 * s + 8 * h + j];
    }
    __syncthreads();

    const int lane = tid & 63;
    const int m    = lane & 31;
    const bool h1  = lane >= 32;

    half8 wf[3];
#pragma unroll
    for (int s = 0; s < 3; ++s) wf[s] = *(const half8*)&ldsA[s][lane][0];

    const int w  = blockIdx.x * (NTHREADS / 64) + (tid >> 6);
    const int t0 = w * TPW;
    const float4* xp = (const float4*)x;
    const float LN2 = 0.69314718055994531f;

    // ---- all TPW*2 global loads issued before any compute ----
    float xv[TPW][D_];
#pragma unroll
    for (int u = 0; u < TPW; ++u) {
        const int n = (t0 + u) * 32 + m;
        float4 a = xp[2 * n], b2 = xp[2 * n + 1];
        xv[u][0] = a.x;  xv[u][1] = a.y;  xv[u][2] = a.z;  xv[u][3] = a.w;
        xv[u][4] = b2.x; xv[u][5] = b2.y; xv[u][6] = b2.z; xv[u][7] = b2.w;
    }

#pragma unroll
    for (int u = 0; u < TPW; ++u) {
        float Y[NF];
        {
            int t = 0;
#pragma unroll
            for (int i = 0; i < D_; ++i)
#pragma unroll
                for (int j = 0; j <= i; ++j) Y[t++] = xv[u][i] * xv[u][j];
#pragma unroll
            for (int i = 0; i < D_; ++i) Y[36 + i] = xv[u][i];
            Y[44] = 1.f; Y[45] = 0.f; Y[46] = 0.f; Y[47] = 0.f;
        }

        f32x16 acc;
#pragma unroll
        for (int r = 0; r < 16; ++r) acc[r] = 0.f;

#pragma unroll
        for (int s = 0; s < 3; ++s) {
            half8 bf;
#pragma unroll
            for (int j = 0; j < 8; ++j) {
                float v = h1 ? Y[16 * s + 8 + j] : Y[16 * s + j];
                bf[j] = (_Float16)v;
            }
            acc = __builtin_amdgcn_mfma_f32_32x32x16_f16(wf[s], bf, acc, 0, 0, 0);
        }

        float tot = 0.f;
#pragma unroll
        for (int r = 0; r < 16; ++r) tot += exp2f(acc[r]);
        tot += __shfl_xor(tot, 32, 64);
        float res = log2f(tot) * LN2;
        if (!h1) out[(t0 + u) * 32 + m] = res;  // coalesced 128B store
    }
}

extern "C" void kernel_launch(void* const* d_in, const int* in_sizes, int n_in,
                              void* d_out, int out_size, void* d_ws, size_t ws_size,
                              hipStream_t stream) {
    const float* x     = (const float*)d_in[0];
    const float* pi    = (const float*)d_in[1];
    const float* means = (const float*)d_in[2];
    const float* chol  = (const float*)d_in[3];
    float* out = (float*)d_out;

    int N = in_sizes[0] / D_;

    gmm_mfma<<<NBLOCKS, NTHREADS, 0, stream>>>(x, pi, means, chol, out, N);
}